// Round 11
// baseline (175.987 us; speedup 1.0000x reference)
//
#include <hip/hip_runtime.h>
#include <hip/hip_bf16.h>

typedef short s16x8 __attribute__((ext_vector_type(8)));
typedef short s16x4 __attribute__((ext_vector_type(4)));
typedef float f32x4 __attribute__((ext_vector_type(4)));
typedef float f32x16 __attribute__((ext_vector_type(16)));
typedef unsigned short u16;
typedef unsigned int u32;
typedef unsigned long long u64;

__device__ __forceinline__ u16 f2bf(float f) {
    union { float f; unsigned u; } c; c.f = f;
    unsigned u = c.u;
    return (u16)((u + 0x7fffu + ((u >> 16) & 1u)) >> 16);
}
__device__ __forceinline__ float bf2f(u32 lo16) {
    union { unsigned u; float f; } c; c.u = lo16 << 16; return c.f;
}
__device__ __forceinline__ u32 cvtpk(float lo, float hi) {
    u32 r;
    asm("v_cvt_pk_bf16_f32 %0, %1, %2" : "=v"(r) : "v"(lo), "v"(hi));
    return r;
}
__device__ __forceinline__ void gload16(const void* g, void* l) {
    __builtin_amdgcn_global_load_lds(
        (const __attribute__((address_space(1))) void*)g,
        (__attribute__((address_space(3))) void*)l, 16, 0, 0);
}

// ---------------- f32 -> bf16 pre-convert (q,k,v, Wq,Wk,Wv,Wo) ----------------
__global__ __launch_bounds__(256)
void conv_k(const float* __restrict__ q, const float* __restrict__ k, const float* __restrict__ v,
            const float* __restrict__ wq, const float* __restrict__ wk, const float* __restrict__ wv,
            const float* __restrict__ wo,
            u16* __restrict__ Qf, u16* __restrict__ Kf, u16* __restrict__ Vf,
            u16* __restrict__ Wqb, u16* __restrict__ Wkb, u16* __restrict__ Wvb, u16* __restrict__ Wob)
{
    const int gi = blockIdx.x * 256 + threadIdx.x;
    const float* src; u16* dst; int base;
    if (gi < 3 * 1048576) {
        const int seg = gi / 1048576;
        base = (gi - seg * 1048576) * 4;
        src = seg == 0 ? q : seg == 1 ? k : v;
        dst = seg == 0 ? Qf : seg == 1 ? Kf : Vf;
    } else {
        const int g2 = gi - 3 * 1048576;
        const int seg = g2 / 262144;
        base = (g2 - seg * 262144) * 4;
        src = seg == 0 ? wq : seg == 1 ? wk : seg == 2 ? wv : wo;
        dst = seg == 0 ? Wqb : seg == 1 ? Wkb : seg == 2 ? Wvb : Wob;
    }
    const float4 x = *(const float4*)(src + base);
    uint2 pk;
    pk.x = f2bf(x.x) | ((unsigned)f2bf(x.y) << 16);
    pk.y = f2bf(x.z) | ((unsigned)f2bf(x.w) << 16);
    *(uint2*)(dst + base) = pk;
}

// ---------------- fused QKV projection: C = A @ W^T + b (round-9 verified) ----
__global__ __launch_bounds__(256)
void qkv_k(const u16* __restrict__ A0, const u16* __restrict__ A1, const u16* __restrict__ A2,
           const u16* __restrict__ W0, const u16* __restrict__ W1, const u16* __restrict__ W2,
           const float* __restrict__ b0, const float* __restrict__ b1, const float* __restrict__ b2,
           u16* __restrict__ O0, u16* __restrict__ O1, u16* __restrict__ O2)
{
    __shared__ u16 As[128 * 64];
    __shared__ u16 Bs[128 * 64];
    const int z = blockIdx.z;
    const u16* A = z == 0 ? A0 : z == 1 ? A1 : A2;
    const u16* W = z == 0 ? W0 : z == 1 ? W1 : W2;
    const float* bias = z == 0 ? b0 : z == 1 ? b1 : b2;
    u16* O = z == 0 ? O0 : z == 1 ? O1 : O2;

    const int tid = threadIdx.x, lane = tid & 63, wave = tid >> 6;
    const int wm = wave >> 1, wn = wave & 1;
    const int g = lane >> 4, q15 = lane & 15;
    const int m0 = blockIdx.x * 128, n0 = blockIdx.y * 128;
    const int srl = lane >> 3;
    const int scs = ((lane & 7) ^ srl) * 8;
    const int sw = q15 & 7;

    f32x4 acc[4][4];
    #pragma unroll
    for (int i = 0; i < 4; i++)
        #pragma unroll
        for (int j = 0; j < 4; j++) acc[i][j] = f32x4{0.f, 0.f, 0.f, 0.f};

    for (int k0 = 0; k0 < 1024; k0 += 64) {
        __syncthreads();
        #pragma unroll
        for (int j = 0; j < 4; j++) {
            const int rb = j * 32 + wave * 8;
            gload16(A + (size_t)(m0 + rb + srl) * 1024 + k0 + scs, &As[rb * 64]);
            gload16(W + (size_t)(n0 + rb + srl) * 1024 + k0 + scs, &Bs[rb * 64]);
        }
        __syncthreads();

        #pragma unroll
        for (int kk = 0; kk < 2; kk++) {
            const int ce = ((kk * 4 + g) ^ sw) * 8;
            s16x8 af[4], bfr[4];
            #pragma unroll
            for (int mi = 0; mi < 4; mi++) af[mi]  = *(const s16x8*)&As[(wm * 64 + mi * 16 + q15) * 64 + ce];
            #pragma unroll
            for (int ni = 0; ni < 4; ni++) bfr[ni] = *(const s16x8*)&Bs[(wn * 64 + ni * 16 + q15) * 64 + ce];
            #pragma unroll
            for (int mi = 0; mi < 4; mi++)
                #pragma unroll
                for (int ni = 0; ni < 4; ni++)
                    acc[mi][ni] = __builtin_amdgcn_mfma_f32_16x16x32_bf16(af[mi], bfr[ni], acc[mi][ni], 0, 0, 0);
        }
    }

    #pragma unroll
    for (int mi = 0; mi < 4; mi++) {
        #pragma unroll
        for (int ni = 0; ni < 4; ni++) {
            const int n = n0 + wn * 64 + ni * 16 + q15;
            const float bn = bias[n];
            const int mbase = m0 + wm * 64 + mi * 16 + g * 4;
            if (z < 2) {
                #pragma unroll
                for (int r = 0; r < 4; r++)
                    O[(size_t)(mbase + r) * 1024 + n] = f2bf(acc[mi][ni][r] + bn);
            } else {
                const int bb = mbase >> 11;
                const int s  = mbase & 2047;
                const int hd = n >> 6, d = n & 63;
                u16 hv[4];
                #pragma unroll
                for (int r = 0; r < 4; r++) hv[r] = f2bf(acc[mi][ni][r] + bn);
                uint2 pk;
                pk.x = hv[0] | ((unsigned)hv[1] << 16);
                pk.y = hv[2] | ((unsigned)hv[3] << 16);
                *(uint2*)&O[(((size_t)(bb * 16 + hd) * 64 + d) << 11) + s] = pk;
            }
        }
    }
}

// ---------------- output projection: C(f32) = A(bf16) @ W^T + b, BK=64 --------
__global__ __launch_bounds__(256)
void og_k(const u16* __restrict__ A, const u16* __restrict__ W,
          const float* __restrict__ bias, float* __restrict__ C)
{
    __shared__ u16 As[64 * 64];
    __shared__ u16 Bs[128 * 64];
    const int tid = threadIdx.x, lane = tid & 63, wave = tid >> 6;
    const int wm = wave >> 1, wn = wave & 1;
    const int g = lane >> 4, q15 = lane & 15;
    const int m0 = blockIdx.x * 64, n0 = blockIdx.y * 128;
    const int srl = lane >> 3;
    const int scs = ((lane & 7) ^ srl) * 8;
    const int sw = q15 & 7;

    f32x4 acc[2][4];
    #pragma unroll
    for (int i = 0; i < 2; i++)
        #pragma unroll
        for (int j = 0; j < 4; j++) acc[i][j] = f32x4{0.f, 0.f, 0.f, 0.f};

    for (int k0 = 0; k0 < 1024; k0 += 64) {
        __syncthreads();
        #pragma unroll
        for (int j = 0; j < 2; j++) {
            const int rb = j * 32 + wave * 8;
            gload16(A + (size_t)(m0 + rb + srl) * 1024 + k0 + scs, &As[rb * 64]);
        }
        #pragma unroll
        for (int j = 0; j < 4; j++) {
            const int rb = j * 32 + wave * 8;
            gload16(W + (size_t)(n0 + rb + srl) * 1024 + k0 + scs, &Bs[rb * 64]);
        }
        __syncthreads();

        #pragma unroll
        for (int kk = 0; kk < 2; kk++) {
            const int ce = ((kk * 4 + g) ^ sw) * 8;
            s16x8 af[2], bfr[4];
            #pragma unroll
            for (int mi = 0; mi < 2; mi++) af[mi]  = *(const s16x8*)&As[(wm * 32 + mi * 16 + q15) * 64 + ce];
            #pragma unroll
            for (int ni = 0; ni < 4; ni++) bfr[ni] = *(const s16x8*)&Bs[(wn * 64 + ni * 16 + q15) * 64 + ce];
            #pragma unroll
            for (int mi = 0; mi < 2; mi++)
                #pragma unroll
                for (int ni = 0; ni < 4; ni++)
                    acc[mi][ni] = __builtin_amdgcn_mfma_f32_16x16x32_bf16(af[mi], bfr[ni], acc[mi][ni], 0, 0, 0);
        }
    }

    #pragma unroll
    for (int mi = 0; mi < 2; mi++) {
        #pragma unroll
        for (int ni = 0; ni < 4; ni++) {
            const int n = n0 + wn * 64 + ni * 16 + q15;
            const float bn = bias[n];
            const int mbase = m0 + wm * 32 + mi * 16 + g * 4;
            #pragma unroll
            for (int r = 0; r < 4; r++)
                C[(size_t)(mbase + r) * 1024 + n] = acc[mi][ni][r] + bn;
        }
    }
}

// ---------------- mask pack: int32 -> bit per position ------------------------
__global__ __launch_bounds__(256)
void pack_mask_k(const int* __restrict__ mask, u64* __restrict__ MB)
{
    const int wid  = blockIdx.x * 4 + (threadIdx.x >> 6);
    const int lane = threadIdx.x & 63;
    const int v = mask[(size_t)wid * 64 + lane];
    const u64 bits = __ballot(v != 0);
    if (lane == 0) MB[wid] = bits;
}

// ---------------- flash attention: 32x32 MFMA, in-register P, kv-split 2 ------
// t-loop manually unrolled x2 so the LDS double-buffer index is compile-time.
// grid (S/128, H, B*2). Partials: CtxP bf16 [2*B][H][S][64], LsumP f32 [2*B][H][S].
__global__ __launch_bounds__(256, 4)
void attn_k(const u16* __restrict__ Q, const u16* __restrict__ K,
            const u16* __restrict__ Vt, const u64* __restrict__ MB,
            u16* __restrict__ CtxP, float* __restrict__ LsumP)
{
    constexpr int S = 2048;
    __shared__ u16 Ks[2][64][64];
    __shared__ u16 Vs[2][64][64];
    const int tid = threadIdx.x, lane = tid & 63, wave = tid >> 6;
    const int l31 = lane & 31, h = lane >> 5, x7 = lane & 7;
    const int hh = blockIdx.y;
    const int b = blockIdx.z >> 1, half = blockIdx.z & 1;
    const int qw = blockIdx.x * 128 + wave * 32;
    const int t0 = half * 16;

    const size_t kgbase = (size_t)b * S * 1024 + hh * 64;
    const size_t vgbase = (size_t)(b * 16 + hh) * 64 * 2048;

    s16x8 qf[4];
    #pragma unroll
    for (int s = 0; s < 4; s++)
        qf[s] = *(const s16x8*)(Q + ((size_t)b * S + qw + l31) * 1024 + hh * 64 + s * 16 + h * 8);

    f32x16 acc[2];
    #pragma unroll
    for (int r = 0; r < 16; r++) { acc[0][r] = 0.f; acc[1][r] = 0.f; }
    float lsum = 0.f;

    const int srl = lane >> 3;
    const int scs = ((lane & 7) ^ srl) * 8;
    auto STAGE = [&](int buf, int kv0) {
        #pragma unroll
        for (int i = 0; i < 2; i++) {
            const int rb = i * 32 + wave * 8;
            gload16(K + kgbase + (size_t)(kv0 + rb + srl) * 1024 + scs, &Ks[buf][rb][0]);
            gload16(Vt + vgbase + (size_t)(rb + srl) * 2048 + kv0 + scs, &Vs[buf][rb][0]);
        }
    };

    const u64* mwp = MB + ((size_t)b * S + qw + l31) * 32 + t0;
    STAGE(0, t0 * 64);

#define ATTN_ITER(T, BUF)                                                           \
    {                                                                               \
        const u64 mw = mwp[T];                                                      \
        if ((T) < 15) {                                                             \
            STAGE((BUF) ^ 1, (t0 + (T) + 1) * 64);                                  \
            asm volatile("s_waitcnt vmcnt(4)" ::: "memory");                        \
        } else {                                                                    \
            asm volatile("s_waitcnt vmcnt(0)" ::: "memory");                        \
        }                                                                           \
        __builtin_amdgcn_s_barrier();                                               \
        __builtin_amdgcn_sched_barrier(0);                                          \
        f32x16 sc[2];                                                               \
        _Pragma("unroll")                                                           \
        for (int r = 0; r < 16; r++) { sc[0][r] = 0.f; sc[1][r] = 0.f; }            \
        __builtin_amdgcn_s_setprio(1);                                              \
        _Pragma("unroll")                                                           \
        for (int s = 0; s < 4; s++) {                                               \
            const int ce = (((s << 1) | h) ^ x7) << 3;                              \
            const s16x8 ka0 = *(const s16x8*)&Ks[BUF][l31][ce];                     \
            const s16x8 ka1 = *(const s16x8*)&Ks[BUF][32 + l31][ce];                \
            sc[0] = __builtin_amdgcn_mfma_f32_32x32x16_bf16(ka0, qf[s], sc[0], 0, 0, 0); \
            sc[1] = __builtin_amdgcn_mfma_f32_32x32x16_bf16(ka1, qf[s], sc[1], 0, 0, 0); \
        }                                                                           \
        __builtin_amdgcn_s_setprio(0);                                              \
        s16x8 pa[4];                                                                \
        _Pragma("unroll")                                                           \
        for (int kvb = 0; kvb < 2; kvb++) {                                         \
            const u32 mh = ((u32)(mw >> (kvb * 32))) >> (h * 4);                    \
            float p[16];                                                            \
            _Pragma("unroll")                                                       \
            for (int r = 0; r < 16; r++) {                                          \
                const int bit = (r & 3) + ((r >> 2) << 3);                          \
                const float e = __builtin_amdgcn_exp2f(fmaf(sc[kvb][r], 0.18033688f, -11.5415603f)); \
                p[r] = ((mh >> bit) & 1u) ? e : 0.f;                                \
            }                                                                       \
            lsum += (((p[0] + p[1]) + (p[2] + p[3])) + ((p[4] + p[5]) + (p[6] + p[7]))) \
                  + (((p[8] + p[9]) + (p[10] + p[11])) + ((p[12] + p[13]) + (p[14] + p[15]))); \
            _Pragma("unroll")                                                       \
            for (int sub = 0; sub < 2; sub++) {                                     \
                const int base = sub * 8;                                           \
                union { u32 w[4]; s16x8 v; } u;                                     \
                u.w[0] = cvtpk(p[base + 0], p[base + 1]);                           \
                u.w[1] = cvtpk(p[base + 2], p[base + 3]);                           \
                u.w[2] = cvtpk(p[base + 4], p[base + 5]);                           \
                u.w[3] = cvtpk(p[base + 6], p[base + 7]);                           \
                pa[kvb * 2 + sub] = u.v;                                            \
            }                                                                       \
        }                                                                           \
        __builtin_amdgcn_s_setprio(1);                                              \
        _Pragma("unroll")                                                           \
        for (int s = 0; s < 4; s++) {                                               \
            const int e0 = (((2 * s)     ^ x7) << 3) + 4 * h;                       \
            const int e1 = (((2 * s + 1) ^ x7) << 3) + 4 * h;                       \
            union { s16x4 q2[2]; s16x8 v; } u0, u1;                                 \
            u0.q2[0] = *(const s16x4*)&Vs[BUF][l31][e0];                            \
            u0.q2[1] = *(const s16x4*)&Vs[BUF][l31][e1];                            \
            u1.q2[0] = *(const s16x4*)&Vs[BUF][32 + l31][e0];                       \
            u1.q2[1] = *(const s16x4*)&Vs[BUF][32 + l31][e1];                       \
            acc[0] = __builtin_amdgcn_mfma_f32_32x32x16_bf16(pa[s], u0.v, acc[0], 0, 0, 0); \
            acc[1] = __builtin_amdgcn_mfma_f32_32x32x16_bf16(pa[s], u1.v, acc[1], 0, 0, 0); \
        }                                                                           \
        __builtin_amdgcn_s_setprio(0);                                              \
        __builtin_amdgcn_s_barrier();                                               \
    }

    for (int tt = 0; tt < 16; tt += 2) {
        ATTN_ITER(tt, 0);
        ATTN_ITER(tt + 1, 1);
    }
#undef ATTN_ITER

    lsum += __shfl_xor(lsum, 32, 64);
    const size_t pbase = (size_t)((half * 2 + b) * 16 + hh) * S;
    if (lane < 32) LsumP[pbase + qw + l31] = lsum;

    #pragma unroll
    for (int db = 0; db < 2; db++)
        #pragma unroll
        for (int r = 0; r < 16; r += 2) {
            const int q1 = qw + (r & 3) + ((r >> 2) << 3) + h * 4;
            const u32 w = cvtpk(acc[db][r], acc[db][r + 1]);
            CtxP[(pbase + q1) * 64 + db * 32 + l31]     = (u16)(w & 0xffffu);
            CtxP[(pbase + q1 + 1) * 64 + db * 32 + l31] = (u16)(w >> 16);
        }
}

// ---------------- combine halves: ctx = (a0+a1)/(l0+l1) -----------------------
__global__ __launch_bounds__(256)
void comb_k(const u16* __restrict__ CtxP, const float* __restrict__ LsumP,
            u16* __restrict__ Cx)
{
    const int gid = blockIdx.x * 256 + threadIdx.x;     // 1,048,576 total
    const int d4 = gid & 15;
    const int q  = (gid >> 4) & 2047;
    const int hd = (gid >> 15) & 15;
    const int bb = gid >> 19;
    const size_t i0 = ((size_t)(bb * 16 + hd)) * 2048 + q;
    const size_t i1 = ((size_t)((2 + bb) * 16 + hd)) * 2048 + q;
    const uint2 a = *(const uint2*)&CtxP[i0 * 64 + d4 * 4];
    const uint2 c = *(const uint2*)&CtxP[i1 * 64 + d4 * 4];
    const float rinv = __builtin_amdgcn_rcpf(LsumP[i0] + LsumP[i1]);
    const u32 au[2] = {a.x, a.y}, cu[2] = {c.x, c.y};
    uint2 o;
    u32 ow[2];
    #pragma unroll
    for (int j = 0; j < 2; j++) {
        const float lo = (bf2f(au[j] & 0xffffu) + bf2f(cu[j] & 0xffffu)) * rinv;
        const float hi = (bf2f(au[j] >> 16)     + bf2f(cu[j] >> 16))     * rinv;
        ow[j] = f2bf(lo) | ((u32)f2bf(hi) << 16);
    }
    o.x = ow[0]; o.y = ow[1];
    *(uint2*)&Cx[((size_t)bb * 2048 + q) * 1024 + hd * 64 + d4 * 4] = o;
}

extern "C" void kernel_launch(void* const* d_in, const int* in_sizes, int n_in,
                              void* d_out, int out_size, void* d_ws, size_t ws_size,
                              hipStream_t stream)
{
    const float* query = (const float*)d_in[0];
    const float* key_  = (const float*)d_in[1];
    const float* value = (const float*)d_in[2];
    const int*   mask  = (const int*)d_in[3];
    const float* Wq = (const float*)d_in[4];
    const float* bq = (const float*)d_in[5];
    const float* Wk = (const float*)d_in[6];
    const float* bk = (const float*)d_in[7];
    const float* Wv = (const float*)d_in[8];
    const float* bv = (const float*)d_in[9];
    const float* Wo = (const float*)d_in[10];
    const float* bo = (const float*)d_in[11];

    char* ws = (char*)d_ws;
    u16* Qf   = (u16*)(ws);                        // 8 MB ; [0,16) reused as CtxP
    u16* Kf   = (u16*)(ws + (size_t)( 8 << 20));   // 8 MB
    u16* Vf   = (u16*)(ws + (size_t)(16 << 20));   // 8 MB
    u16* Wqb  = (u16*)(ws + (size_t)(24 << 20));   // 2 MB
    u16* Wkb  = (u16*)(ws + (size_t)(26 << 20));   // 2 MB
    u16* Wvb  = (u16*)(ws + (size_t)(28 << 20));   // 2 MB
    u16* Wob  = (u16*)(ws + (size_t)(30 << 20));   // 2 MB
    u16* Qb   = (u16*)(ws + (size_t)(32 << 20));   // 8 MB ; reused as Cx
    u16* Kb   = (u16*)(ws + (size_t)(40 << 20));   // 8 MB
    u16* Vt   = (u16*)(ws + (size_t)(48 << 20));   // 8 MB
    u64* MBp  = (u64*)(ws + (size_t)(56 << 20));   // 1 MB
    float* LsP = (float*)(ws + (size_t)(57 << 20));// 0.5 MB
    u16* CtxP = Qf;   // 16 MB partials, Qf/Kf dead after qkv_k
    u16* Cx   = Qb;   // Qb dead after attn_k

    dim3 bb2(256, 1, 1);
    conv_k<<<dim3(16384, 1, 1), bb2, 0, stream>>>(query, key_, value, Wq, Wk, Wv, Wo,
                                                  Qf, Kf, Vf, Wqb, Wkb, Wvb, Wob);
    qkv_k<<<dim3(32, 8, 3), bb2, 0, stream>>>(Qf, Kf, Vf, Wqb, Wkb, Wvb,
                                              bq, bk, bv, Qb, Kb, Vt);
    pack_mask_k<<<dim3(32768, 1, 1), bb2, 0, stream>>>(mask, MBp);
    attn_k<<<dim3(16, 16, 4), bb2, 0, stream>>>(Qb, Kb, Vt, MBp, CtxP, LsP);
    comb_k<<<dim3(4096, 1, 1), bb2, 0, stream>>>(CtxP, LsP, Cx);
    og_k<<<dim3(64, 8, 1), bb2, 0, stream>>>(Cx, Wob, bo, (float*)d_out);
}

// Round 12
// 153.087 us; speedup vs baseline: 1.1496x; 1.1496x over previous
//
#include <hip/hip_runtime.h>
#include <hip/hip_bf16.h>

typedef short s16x8 __attribute__((ext_vector_type(8)));
typedef short s16x4 __attribute__((ext_vector_type(4)));
typedef float f32x4 __attribute__((ext_vector_type(4)));
typedef float f32x16 __attribute__((ext_vector_type(16)));
typedef unsigned short u16;
typedef unsigned int u32;
typedef unsigned long long u64;

__device__ __forceinline__ u16 f2bf(float f) {
    union { float f; unsigned u; } c; c.f = f;
    unsigned u = c.u;
    return (u16)((u + 0x7fffu + ((u >> 16) & 1u)) >> 16);
}
__device__ __forceinline__ float bf2f(u32 lo16) {
    union { unsigned u; float f; } c; c.u = lo16 << 16; return c.f;
}
__device__ __forceinline__ u32 cvtpk(float lo, float hi) {
    u32 r;
    asm("v_cvt_pk_bf16_f32 %0, %1, %2" : "=v"(r) : "v"(lo), "v"(hi));
    return r;
}
__device__ __forceinline__ void gload16(const void* g, void* l) {
    __builtin_amdgcn_global_load_lds(
        (const __attribute__((address_space(1))) void*)g,
        (__attribute__((address_space(3))) void*)l, 16, 0, 0);
}

// ---------------- f32 -> bf16 pre-convert (weights only) ----------------------
__global__ __launch_bounds__(256)
void conv_k(const float* __restrict__ wq, const float* __restrict__ wk,
            const float* __restrict__ wv, const float* __restrict__ wo,
            u16* __restrict__ Wqb, u16* __restrict__ Wkb,
            u16* __restrict__ Wvb, u16* __restrict__ Wob)
{
    const int gi = blockIdx.x * 256 + threadIdx.x;   // 1,048,576 float4 groups
    const int seg = gi >> 18;
    const int base = (gi & 262143) * 4;
    const float* src = seg == 0 ? wq : seg == 1 ? wk : seg == 2 ? wv : wo;
    u16* dst = seg == 0 ? Wqb : seg == 1 ? Wkb : seg == 2 ? Wvb : Wob;
    const float4 x = *(const float4*)(src + base);
    uint2 pk;
    pk.x = f2bf(x.x) | ((unsigned)f2bf(x.y) << 16);
    pk.y = f2bf(x.z) | ((unsigned)f2bf(x.w) << 16);
    *(uint2*)(dst + base) = pk;
}

// ---------------- fused QKV projection: C = A(f32) @ W^T + b ------------------
// A read as f32 with reg-staging (loads issued before barrier, cvt_pk, swizzled
// ds_write_b64 into the same XOR layout the verified read side uses).
// B (weights bf16) staged via global_load_lds. BK=64.
__global__ __launch_bounds__(256)
void qkv_k(const float* __restrict__ A0, const float* __restrict__ A1, const float* __restrict__ A2,
           const u16* __restrict__ W0, const u16* __restrict__ W1, const u16* __restrict__ W2,
           const float* __restrict__ b0, const float* __restrict__ b1, const float* __restrict__ b2,
           u16* __restrict__ O0, u16* __restrict__ O1, u16* __restrict__ O2)
{
    __shared__ u16 As[128 * 64];
    __shared__ u16 Bs[128 * 64];
    const int z = blockIdx.z;
    const float* A = z == 0 ? A0 : z == 1 ? A1 : A2;
    const u16* W = z == 0 ? W0 : z == 1 ? W1 : W2;
    const float* bias = z == 0 ? b0 : z == 1 ? b1 : b2;
    u16* O = z == 0 ? O0 : z == 1 ? O1 : O2;

    const int tid = threadIdx.x, lane = tid & 63, wave = tid >> 6;
    const int wm = wave >> 1, wn = wave & 1;
    const int g = lane >> 4, q15 = lane & 15;
    const int m0 = blockIdx.x * 128, n0 = blockIdx.y * 128;
    // B staging (gload_lds, linear dest + inverse-swizzled source)
    const int srl = lane >> 3;
    const int scs = ((lane & 7) ^ srl) * 8;
    const int sw = q15 & 7;
    // A staging (reg): 16 threads/row, one float4 each; 8 passes of 16 rows
    const int arow_l = tid >> 4;            // 0..15 row within pass
    const int fcol = (tid & 15) * 4;        // f32 col
    const int chunk = fcol >> 3;            // 8-elem chunk index (0..7)
    const int within = fcol & 7;            // 0 or 4

    f32x4 acc[4][4];
    #pragma unroll
    for (int i = 0; i < 4; i++)
        #pragma unroll
        for (int j = 0; j < 4; j++) acc[i][j] = f32x4{0.f, 0.f, 0.f, 0.f};

    for (int k0 = 0; k0 < 1024; k0 += 64) {
        // issue A loads early: latency hides under prev compute + barrier
        float4 av[8];
        #pragma unroll
        for (int p = 0; p < 8; p++) {
            const int row = p * 16 + arow_l;
            av[p] = *(const float4*)(A + (size_t)(m0 + row) * 1024 + k0 + fcol);
        }
        __syncthreads();
        #pragma unroll
        for (int j = 0; j < 4; j++) {
            const int rb = j * 32 + wave * 8;
            gload16(W + (size_t)(n0 + rb + srl) * 1024 + k0 + scs, &Bs[rb * 64]);
        }
        #pragma unroll
        for (int p = 0; p < 8; p++) {
            const int row = p * 16 + arow_l;
            const int schunk = chunk ^ (row & 7);
            uint2 pk;
            pk.x = cvtpk(av[p].x, av[p].y);
            pk.y = cvtpk(av[p].z, av[p].w);
            *(uint2*)&As[row * 64 + schunk * 8 + within] = pk;
        }
        __syncthreads();

        #pragma unroll
        for (int kk = 0; kk < 2; kk++) {
            const int ce = ((kk * 4 + g) ^ sw) * 8;
            s16x8 af[4], bfr[4];
            #pragma unroll
            for (int mi = 0; mi < 4; mi++) af[mi]  = *(const s16x8*)&As[(wm * 64 + mi * 16 + q15) * 64 + ce];
            #pragma unroll
            for (int ni = 0; ni < 4; ni++) bfr[ni] = *(const s16x8*)&Bs[(wn * 64 + ni * 16 + q15) * 64 + ce];
            #pragma unroll
            for (int mi = 0; mi < 4; mi++)
                #pragma unroll
                for (int ni = 0; ni < 4; ni++)
                    acc[mi][ni] = __builtin_amdgcn_mfma_f32_16x16x32_bf16(af[mi], bfr[ni], acc[mi][ni], 0, 0, 0);
        }
    }

    #pragma unroll
    for (int mi = 0; mi < 4; mi++) {
        #pragma unroll
        for (int ni = 0; ni < 4; ni++) {
            const int n = n0 + wn * 64 + ni * 16 + q15;
            const float bn = bias[n];
            const int mbase = m0 + wm * 64 + mi * 16 + g * 4;
            if (z < 2) {
                #pragma unroll
                for (int r = 0; r < 4; r++)
                    O[(size_t)(mbase + r) * 1024 + n] = f2bf(acc[mi][ni][r] + bn);
            } else {
                const int bb = mbase >> 11;
                const int s  = mbase & 2047;
                const int hd = n >> 6, d = n & 63;
                u16 hv[4];
                #pragma unroll
                for (int r = 0; r < 4; r++) hv[r] = f2bf(acc[mi][ni][r] + bn);
                uint2 pk;
                pk.x = hv[0] | ((unsigned)hv[1] << 16);
                pk.y = hv[2] | ((unsigned)hv[3] << 16);
                *(uint2*)&O[(((size_t)(bb * 16 + hd) * 64 + d) << 11) + s] = pk;
            }
        }
    }
}

// ---------------- output projection: C(f32) = A(bf16) @ W^T + b, BK=64 --------
__global__ __launch_bounds__(256)
void og_k(const u16* __restrict__ A, const u16* __restrict__ W,
          const float* __restrict__ bias, float* __restrict__ C)
{
    __shared__ u16 As[64 * 64];
    __shared__ u16 Bs[128 * 64];
    const int tid = threadIdx.x, lane = tid & 63, wave = tid >> 6;
    const int wm = wave >> 1, wn = wave & 1;
    const int g = lane >> 4, q15 = lane & 15;
    const int m0 = blockIdx.x * 64, n0 = blockIdx.y * 128;
    const int srl = lane >> 3;
    const int scs = ((lane & 7) ^ srl) * 8;
    const int sw = q15 & 7;

    f32x4 acc[2][4];
    #pragma unroll
    for (int i = 0; i < 2; i++)
        #pragma unroll
        for (int j = 0; j < 4; j++) acc[i][j] = f32x4{0.f, 0.f, 0.f, 0.f};

    for (int k0 = 0; k0 < 1024; k0 += 64) {
        __syncthreads();
        #pragma unroll
        for (int j = 0; j < 2; j++) {
            const int rb = j * 32 + wave * 8;
            gload16(A + (size_t)(m0 + rb + srl) * 1024 + k0 + scs, &As[rb * 64]);
        }
        #pragma unroll
        for (int j = 0; j < 4; j++) {
            const int rb = j * 32 + wave * 8;
            gload16(W + (size_t)(n0 + rb + srl) * 1024 + k0 + scs, &Bs[rb * 64]);
        }
        __syncthreads();

        #pragma unroll
        for (int kk = 0; kk < 2; kk++) {
            const int ce = ((kk * 4 + g) ^ sw) * 8;
            s16x8 af[2], bfr[4];
            #pragma unroll
            for (int mi = 0; mi < 2; mi++) af[mi]  = *(const s16x8*)&As[(wm * 32 + mi * 16 + q15) * 64 + ce];
            #pragma unroll
            for (int ni = 0; ni < 4; ni++) bfr[ni] = *(const s16x8*)&Bs[(wn * 64 + ni * 16 + q15) * 64 + ce];
            #pragma unroll
            for (int mi = 0; mi < 2; mi++)
                #pragma unroll
                for (int ni = 0; ni < 4; ni++)
                    acc[mi][ni] = __builtin_amdgcn_mfma_f32_16x16x32_bf16(af[mi], bfr[ni], acc[mi][ni], 0, 0, 0);
        }
    }

    #pragma unroll
    for (int mi = 0; mi < 2; mi++) {
        #pragma unroll
        for (int ni = 0; ni < 4; ni++) {
            const int n = n0 + wn * 64 + ni * 16 + q15;
            const float bn = bias[n];
            const int mbase = m0 + wm * 32 + mi * 16 + g * 4;
            #pragma unroll
            for (int r = 0; r < 4; r++)
                C[(size_t)(mbase + r) * 1024 + n] = acc[mi][ni][r] + bn;
        }
    }
}

// ---------------- mask pack: int32 -> bit per position ------------------------
__global__ __launch_bounds__(256)
void pack_mask_k(const int* __restrict__ mask, u64* __restrict__ MB)
{
    const int wid  = blockIdx.x * 4 + (threadIdx.x >> 6);
    const int lane = threadIdx.x & 63;
    const int v = mask[(size_t)wid * 64 + lane];
    const u64 bits = __ballot(v != 0);
    if (lane == 0) MB[wid] = bits;
}

// ---------------- flash attention: 32x32 MFMA, in-register P (round-9) --------
__global__ __launch_bounds__(256, 4)
void attn_k(const u16* __restrict__ Q, const u16* __restrict__ K,
            const u16* __restrict__ Vt, const u64* __restrict__ MB,
            u16* __restrict__ CtxP, float* __restrict__ LsumP)
{
    constexpr int S = 2048;
    __shared__ u16 Ks[2][64][64];
    __shared__ u16 Vs[2][64][64];
    const int tid = threadIdx.x, lane = tid & 63, wave = tid >> 6;
    const int l31 = lane & 31, h = lane >> 5, x7 = lane & 7;
    const int hh = blockIdx.y;
    const int b = blockIdx.z >> 1, half = blockIdx.z & 1;
    const int qw = blockIdx.x * 128 + wave * 32;
    const int t0 = half * 16;

    const size_t kgbase = (size_t)b * S * 1024 + hh * 64;
    const size_t vgbase = (size_t)(b * 16 + hh) * 64 * 2048;

    s16x8 qf[4];
    #pragma unroll
    for (int s = 0; s < 4; s++)
        qf[s] = *(const s16x8*)(Q + ((size_t)b * S + qw + l31) * 1024 + hh * 64 + s * 16 + h * 8);

    f32x16 acc[2];
    #pragma unroll
    for (int r = 0; r < 16; r++) { acc[0][r] = 0.f; acc[1][r] = 0.f; }
    float lsum = 0.f;

    const int srl = lane >> 3;
    const int scs = ((lane & 7) ^ srl) * 8;
    auto STAGE = [&](int buf, int kv0) {
        #pragma unroll
        for (int i = 0; i < 2; i++) {
            const int rb = i * 32 + wave * 8;
            gload16(K + kgbase + (size_t)(kv0 + rb + srl) * 1024 + scs, &Ks[buf][rb][0]);
            gload16(Vt + vgbase + (size_t)(rb + srl) * 2048 + kv0 + scs, &Vs[buf][rb][0]);
        }
    };

    const u64* mwp = MB + ((size_t)b * S + qw + l31) * 32 + t0;
    STAGE(0, t0 * 64);

    for (int t = 0; t < 16; t++) {
        const int buf = t & 1;
        const u64 mw = mwp[t];
        if (t < 15) {
            STAGE(buf ^ 1, (t0 + t + 1) * 64);
            asm volatile("s_waitcnt vmcnt(4)" ::: "memory");
        } else {
            asm volatile("s_waitcnt vmcnt(0)" ::: "memory");
        }
        __builtin_amdgcn_s_barrier();
        __builtin_amdgcn_sched_barrier(0);

        f32x16 sc[2];
        #pragma unroll
        for (int r = 0; r < 16; r++) { sc[0][r] = 0.f; sc[1][r] = 0.f; }
        __builtin_amdgcn_s_setprio(1);
        #pragma unroll
        for (int s = 0; s < 4; s++) {
            const int ce = (((s << 1) | h) ^ x7) << 3;
            const s16x8 ka0 = *(const s16x8*)&Ks[buf][l31][ce];
            const s16x8 ka1 = *(const s16x8*)&Ks[buf][32 + l31][ce];
            sc[0] = __builtin_amdgcn_mfma_f32_32x32x16_bf16(ka0, qf[s], sc[0], 0, 0, 0);
            sc[1] = __builtin_amdgcn_mfma_f32_32x32x16_bf16(ka1, qf[s], sc[1], 0, 0, 0);
        }
        __builtin_amdgcn_s_setprio(0);

        s16x8 pa[4];
        #pragma unroll
        for (int kvb = 0; kvb < 2; kvb++) {
            const u32 mh = ((u32)(mw >> (kvb * 32))) >> (h * 4);
            float p[16];
            #pragma unroll
            for (int r = 0; r < 16; r++) {
                const int bit = (r & 3) + ((r >> 2) << 3);
                const float e = __builtin_amdgcn_exp2f(fmaf(sc[kvb][r], 0.18033688f, -11.5415603f));
                p[r] = ((mh >> bit) & 1u) ? e : 0.f;
            }
            lsum += (((p[0] + p[1]) + (p[2] + p[3])) + ((p[4] + p[5]) + (p[6] + p[7])))
                  + (((p[8] + p[9]) + (p[10] + p[11])) + ((p[12] + p[13]) + (p[14] + p[15])));
            #pragma unroll
            for (int sub = 0; sub < 2; sub++) {
                const int base = sub * 8;
                union { u32 w[4]; s16x8 v; } u;
                u.w[0] = cvtpk(p[base + 0], p[base + 1]);
                u.w[1] = cvtpk(p[base + 2], p[base + 3]);
                u.w[2] = cvtpk(p[base + 4], p[base + 5]);
                u.w[3] = cvtpk(p[base + 6], p[base + 7]);
                pa[kvb * 2 + sub] = u.v;
            }
        }

        __builtin_amdgcn_s_setprio(1);
        #pragma unroll
        for (int s = 0; s < 4; s++) {
            const int e0 = (((2 * s)     ^ x7) << 3) + 4 * h;
            const int e1 = (((2 * s + 1) ^ x7) << 3) + 4 * h;
            union { s16x4 q2[2]; s16x8 v; } u0, u1;
            u0.q2[0] = *(const s16x4*)&Vs[buf][l31][e0];
            u0.q2[1] = *(const s16x4*)&Vs[buf][l31][e1];
            u1.q2[0] = *(const s16x4*)&Vs[buf][32 + l31][e0];
            u1.q2[1] = *(const s16x4*)&Vs[buf][32 + l31][e1];
            acc[0] = __builtin_amdgcn_mfma_f32_32x32x16_bf16(pa[s], u0.v, acc[0], 0, 0, 0);
            acc[1] = __builtin_amdgcn_mfma_f32_32x32x16_bf16(pa[s], u1.v, acc[1], 0, 0, 0);
        }
        __builtin_amdgcn_s_setprio(0);
        __builtin_amdgcn_s_barrier();
    }

    lsum += __shfl_xor(lsum, 32, 64);
    const size_t pbase = (size_t)((half * 2 + b) * 16 + hh) * S;
    if (lane < 32) LsumP[pbase + qw + l31] = lsum;

    #pragma unroll
    for (int db = 0; db < 2; db++)
        #pragma unroll
        for (int r = 0; r < 16; r += 2) {
            const int q1 = qw + (r & 3) + ((r >> 2) << 3) + h * 4;
            const u32 w = cvtpk(acc[db][r], acc[db][r + 1]);
            CtxP[(pbase + q1) * 64 + db * 32 + l31]     = (u16)(w & 0xffffu);
            CtxP[(pbase + q1 + 1) * 64 + db * 32 + l31] = (u16)(w >> 16);
        }
}

// ---------------- combine halves: ctx = (a0+a1)/(l0+l1) -----------------------
__global__ __launch_bounds__(256)
void comb_k(const u16* __restrict__ CtxP, const float* __restrict__ LsumP,
            u16* __restrict__ Cx)
{
    const int gid = blockIdx.x * 256 + threadIdx.x;     // 1,048,576 total
    const int d4 = gid & 15;
    const int q  = (gid >> 4) & 2047;
    const int hd = (gid >> 15) & 15;
    const int bb = gid >> 19;
    const size_t i0 = ((size_t)(bb * 16 + hd)) * 2048 + q;
    const size_t i1 = ((size_t)((2 + bb) * 16 + hd)) * 2048 + q;
    const uint2 a = *(const uint2*)&CtxP[i0 * 64 + d4 * 4];
    const uint2 c = *(const uint2*)&CtxP[i1 * 64 + d4 * 4];
    const float rinv = __builtin_amdgcn_rcpf(LsumP[i0] + LsumP[i1]);
    const u32 au[2] = {a.x, a.y}, cu[2] = {c.x, c.y};
    uint2 o;
    u32 ow[2];
    #pragma unroll
    for (int j = 0; j < 2; j++) {
        const float lo = (bf2f(au[j] & 0xffffu) + bf2f(cu[j] & 0xffffu)) * rinv;
        const float hi = (bf2f(au[j] >> 16)     + bf2f(cu[j] >> 16))     * rinv;
        ow[j] = f2bf(lo) | ((u32)f2bf(hi) << 16);
    }
    o.x = ow[0]; o.y = ow[1];
    *(uint2*)&Cx[((size_t)bb * 2048 + q) * 1024 + hd * 64 + d4 * 4] = o;
}

extern "C" void kernel_launch(void* const* d_in, const int* in_sizes, int n_in,
                              void* d_out, int out_size, void* d_ws, size_t ws_size,
                              hipStream_t stream)
{
    const float* query = (const float*)d_in[0];
    const float* key_  = (const float*)d_in[1];
    const float* value = (const float*)d_in[2];
    const int*   mask  = (const int*)d_in[3];
    const float* Wq = (const float*)d_in[4];
    const float* bq = (const float*)d_in[5];
    const float* Wk = (const float*)d_in[6];
    const float* bk = (const float*)d_in[7];
    const float* Wv = (const float*)d_in[8];
    const float* bv = (const float*)d_in[9];
    const float* Wo = (const float*)d_in[10];
    const float* bo = (const float*)d_in[11];

    char* ws = (char*)d_ws;
    u16* CtxP = (u16*)(ws);                        // 16 MB attn partials [0,16)
    u16* Wqb  = (u16*)(ws + (size_t)(24 << 20));   // 2 MB
    u16* Wkb  = (u16*)(ws + (size_t)(26 << 20));   // 2 MB
    u16* Wvb  = (u16*)(ws + (size_t)(28 << 20));   // 2 MB
    u16* Wob  = (u16*)(ws + (size_t)(30 << 20));   // 2 MB
    u16* Qb   = (u16*)(ws + (size_t)(32 << 20));   // 8 MB ; reused as Cx
    u16* Kb   = (u16*)(ws + (size_t)(40 << 20));   // 8 MB
    u16* Vt   = (u16*)(ws + (size_t)(48 << 20));   // 8 MB
    u64* MBp  = (u64*)(ws + (size_t)(56 << 20));   // 1 MB
    float* LsP = (float*)(ws + (size_t)(57 << 20));// 0.5 MB
    u16* Cx   = Qb;   // Qb dead after attn_k

    dim3 bb2(256, 1, 1);
    conv_k<<<dim3(4096, 1, 1), bb2, 0, stream>>>(Wq, Wk, Wv, Wo, Wqb, Wkb, Wvb, Wob);
    qkv_k<<<dim3(32, 8, 3), bb2, 0, stream>>>(query, key_, value, Wqb, Wkb, Wvb,
                                              bq, bk, bv, Qb, Kb, Vt);
    pack_mask_k<<<dim3(32768, 1, 1), bb2, 0, stream>>>(mask, MBp);
    attn_k<<<dim3(16, 16, 4), bb2, 0, stream>>>(Qb, Kb, Vt, MBp, CtxP, LsP);
    comb_k<<<dim3(4096, 1, 1), bb2, 0, stream>>>(CtxP, LsP, Cx);
    og_k<<<dim3(64, 8, 1), bb2, 0, stream>>>(Cx, Wob, bo, (float*)d_out);
}

// Round 13
// 147.790 us; speedup vs baseline: 1.1908x; 1.0358x over previous
//
#include <hip/hip_runtime.h>
#include <hip/hip_bf16.h>

typedef short s16x8 __attribute__((ext_vector_type(8)));
typedef short s16x4 __attribute__((ext_vector_type(4)));
typedef float f32x4 __attribute__((ext_vector_type(4)));
typedef float f32x16 __attribute__((ext_vector_type(16)));
typedef unsigned short u16;
typedef unsigned int u32;
typedef unsigned long long u64;

__device__ __forceinline__ u16 f2bf(float f) {
    union { float f; unsigned u; } c; c.f = f;
    unsigned u = c.u;
    return (u16)((u + 0x7fffu + ((u >> 16) & 1u)) >> 16);
}
__device__ __forceinline__ float bf2f(u32 lo16) {
    union { unsigned u; float f; } c; c.u = lo16 << 16; return c.f;
}
__device__ __forceinline__ u32 cvtpk(float lo, float hi) {
    u32 r;
    asm("v_cvt_pk_bf16_f32 %0, %1, %2" : "=v"(r) : "v"(lo), "v"(hi));
    return r;
}
__device__ __forceinline__ void gload16(const void* g, void* l) {
    __builtin_amdgcn_global_load_lds(
        (const __attribute__((address_space(1))) void*)g,
        (__attribute__((address_space(3))) void*)l, 16, 0, 0);
}

// ---------------- f32 -> bf16 pre-convert (weights only) ----------------------
__global__ __launch_bounds__(256)
void conv_k(const float* __restrict__ wq, const float* __restrict__ wk,
            const float* __restrict__ wv, const float* __restrict__ wo,
            u16* __restrict__ Wqb, u16* __restrict__ Wkb,
            u16* __restrict__ Wvb, u16* __restrict__ Wob)
{
    const int gi = blockIdx.x * 256 + threadIdx.x;   // 1,048,576 float4 groups
    const int seg = gi >> 18;
    const int base = (gi & 262143) * 4;
    const float* src = seg == 0 ? wq : seg == 1 ? wk : seg == 2 ? wv : wo;
    u16* dst = seg == 0 ? Wqb : seg == 1 ? Wkb : seg == 2 ? Wvb : Wob;
    const float4 x = *(const float4*)(src + base);
    uint2 pk;
    pk.x = f2bf(x.x) | ((unsigned)f2bf(x.y) << 16);
    pk.y = f2bf(x.z) | ((unsigned)f2bf(x.w) << 16);
    *(uint2*)(dst + base) = pk;
}

// ---------------- fused QKV projection: C = A(f32) @ W^T + b ------------------
// A: f32 reg-staged, software-pipelined (issue next tile's loads during current
// compute; counted vmcnt + raw barriers so prefetch survives the barrier).
// B: bf16 weights via global_load_lds. BK=64, XOR-swizzled LDS.
__global__ __launch_bounds__(256)
void qkv_k(const float* __restrict__ A0, const float* __restrict__ A1, const float* __restrict__ A2,
           const u16* __restrict__ W0, const u16* __restrict__ W1, const u16* __restrict__ W2,
           const float* __restrict__ b0, const float* __restrict__ b1, const float* __restrict__ b2,
           u16* __restrict__ O0, u16* __restrict__ O1, u16* __restrict__ O2)
{
    __shared__ u16 As[128 * 64];
    __shared__ u16 Bs[128 * 64];
    const int z = blockIdx.z;
    const float* A = z == 0 ? A0 : z == 1 ? A1 : A2;
    const u16* W = z == 0 ? W0 : z == 1 ? W1 : W2;
    const float* bias = z == 0 ? b0 : z == 1 ? b1 : b2;
    u16* O = z == 0 ? O0 : z == 1 ? O1 : O2;

    const int tid = threadIdx.x, lane = tid & 63, wave = tid >> 6;
    const int wm = wave >> 1, wn = wave & 1;
    const int g = lane >> 4, q15 = lane & 15;
    const int m0 = blockIdx.x * 128, n0 = blockIdx.y * 128;
    // B staging (gload_lds, linear dest + inverse-swizzled source)
    const int srl = lane >> 3;
    const int scs = ((lane & 7) ^ srl) * 8;
    const int sw = q15 & 7;
    // A staging (reg): 16 threads/row, one float4 each; 8 passes of 16 rows
    const int arow_l = tid >> 4;
    const int fcol = (tid & 15) * 4;
    const int chunk = fcol >> 3;
    const int within = fcol & 7;

    f32x4 acc[4][4];
    #pragma unroll
    for (int i = 0; i < 4; i++)
        #pragma unroll
        for (int j = 0; j < 4; j++) acc[i][j] = f32x4{0.f, 0.f, 0.f, 0.f};

    // prologue: issue A loads for first tile
    float4 av[8];
    #pragma unroll
    for (int p = 0; p < 8; p++)
        av[p] = *(const float4*)(A + (size_t)(m0 + p * 16 + arow_l) * 1024 + fcol);

    for (int k0 = 0; k0 < 1024; k0 += 64) {
        // barrier #1: all waves done reading LDS from previous MFMA phase
        asm volatile("s_waitcnt lgkmcnt(0)" ::: "memory");
        __builtin_amdgcn_s_barrier();

        // stage B (async, direct to LDS)
        #pragma unroll
        for (int j = 0; j < 4; j++) {
            const int rb = j * 32 + wave * 8;
            gload16(W + (size_t)(n0 + rb + srl) * 1024 + k0 + scs, &Bs[rb * 64]);
        }

        // convert previous av (had full MFMA phase to land), freeing av regs
        uint2 pk[8];
        #pragma unroll
        for (int p = 0; p < 8; p++) {
            pk[p].x = cvtpk(av[p].x, av[p].y);
            pk[p].y = cvtpk(av[p].z, av[p].w);
        }
        // issue next tile's A loads — stay in flight across the barrier
        if (k0 < 960) {
            #pragma unroll
            for (int p = 0; p < 8; p++)
                av[p] = *(const float4*)(A + (size_t)(m0 + p * 16 + arow_l) * 1024 + (k0 + 64) + fcol);
        }
        // write A tile (swizzled layout, verified round-12)
        #pragma unroll
        for (int p = 0; p < 8; p++) {
            const int row = p * 16 + arow_l;
            const int schunk = chunk ^ (row & 7);
            *(uint2*)&As[row * 64 + schunk * 8 + within] = pk[p];
        }

        // barrier #2: B gloads + A writes done; av prefetch (8) stays in flight
        if (k0 < 960)
            asm volatile("s_waitcnt vmcnt(8) lgkmcnt(0)" ::: "memory");
        else
            asm volatile("s_waitcnt vmcnt(0) lgkmcnt(0)" ::: "memory");
        __builtin_amdgcn_s_barrier();
        __builtin_amdgcn_sched_barrier(0);

        #pragma unroll
        for (int kk = 0; kk < 2; kk++) {
            const int ce = ((kk * 4 + g) ^ sw) * 8;
            s16x8 af[4], bfr[4];
            #pragma unroll
            for (int mi = 0; mi < 4; mi++) af[mi]  = *(const s16x8*)&As[(wm * 64 + mi * 16 + q15) * 64 + ce];
            #pragma unroll
            for (int ni = 0; ni < 4; ni++) bfr[ni] = *(const s16x8*)&Bs[(wn * 64 + ni * 16 + q15) * 64 + ce];
            #pragma unroll
            for (int mi = 0; mi < 4; mi++)
                #pragma unroll
                for (int ni = 0; ni < 4; ni++)
                    acc[mi][ni] = __builtin_amdgcn_mfma_f32_16x16x32_bf16(af[mi], bfr[ni], acc[mi][ni], 0, 0, 0);
        }
    }

    #pragma unroll
    for (int mi = 0; mi < 4; mi++) {
        #pragma unroll
        for (int ni = 0; ni < 4; ni++) {
            const int n = n0 + wn * 64 + ni * 16 + q15;
            const float bn = bias[n];
            const int mbase = m0 + wm * 64 + mi * 16 + g * 4;
            if (z < 2) {
                #pragma unroll
                for (int r = 0; r < 4; r++)
                    O[(size_t)(mbase + r) * 1024 + n] = f2bf(acc[mi][ni][r] + bn);
            } else {
                const int bb = mbase >> 11;
                const int s  = mbase & 2047;
                const int hd = n >> 6, d = n & 63;
                u16 hv[4];
                #pragma unroll
                for (int r = 0; r < 4; r++) hv[r] = f2bf(acc[mi][ni][r] + bn);
                uint2 pk2;
                pk2.x = hv[0] | ((unsigned)hv[1] << 16);
                pk2.y = hv[2] | ((unsigned)hv[3] << 16);
                *(uint2*)&O[(((size_t)(bb * 16 + hd) * 64 + d) << 11) + s] = pk2;
            }
        }
    }
}

// ---------------- output projection: C(f32) = A(bf16) @ W^T + b, BK=64 --------
__global__ __launch_bounds__(256)
void og_k(const u16* __restrict__ A, const u16* __restrict__ W,
          const float* __restrict__ bias, float* __restrict__ C)
{
    __shared__ u16 As[64 * 64];
    __shared__ u16 Bs[128 * 64];
    const int tid = threadIdx.x, lane = tid & 63, wave = tid >> 6;
    const int wm = wave >> 1, wn = wave & 1;
    const int g = lane >> 4, q15 = lane & 15;
    const int m0 = blockIdx.x * 64, n0 = blockIdx.y * 128;
    const int srl = lane >> 3;
    const int scs = ((lane & 7) ^ srl) * 8;
    const int sw = q15 & 7;

    f32x4 acc[2][4];
    #pragma unroll
    for (int i = 0; i < 2; i++)
        #pragma unroll
        for (int j = 0; j < 4; j++) acc[i][j] = f32x4{0.f, 0.f, 0.f, 0.f};

    for (int k0 = 0; k0 < 1024; k0 += 64) {
        __syncthreads();
        #pragma unroll
        for (int j = 0; j < 2; j++) {
            const int rb = j * 32 + wave * 8;
            gload16(A + (size_t)(m0 + rb + srl) * 1024 + k0 + scs, &As[rb * 64]);
        }
        #pragma unroll
        for (int j = 0; j < 4; j++) {
            const int rb = j * 32 + wave * 8;
            gload16(W + (size_t)(n0 + rb + srl) * 1024 + k0 + scs, &Bs[rb * 64]);
        }
        __syncthreads();

        #pragma unroll
        for (int kk = 0; kk < 2; kk++) {
            const int ce = ((kk * 4 + g) ^ sw) * 8;
            s16x8 af[2], bfr[4];
            #pragma unroll
            for (int mi = 0; mi < 2; mi++) af[mi]  = *(const s16x8*)&As[(wm * 32 + mi * 16 + q15) * 64 + ce];
            #pragma unroll
            for (int ni = 0; ni < 4; ni++) bfr[ni] = *(const s16x8*)&Bs[(wn * 64 + ni * 16 + q15) * 64 + ce];
            #pragma unroll
            for (int mi = 0; mi < 2; mi++)
                #pragma unroll
                for (int ni = 0; ni < 4; ni++)
                    acc[mi][ni] = __builtin_amdgcn_mfma_f32_16x16x32_bf16(af[mi], bfr[ni], acc[mi][ni], 0, 0, 0);
        }
    }

    #pragma unroll
    for (int mi = 0; mi < 2; mi++) {
        #pragma unroll
        for (int ni = 0; ni < 4; ni++) {
            const int n = n0 + wn * 64 + ni * 16 + q15;
            const float bn = bias[n];
            const int mbase = m0 + wm * 32 + mi * 16 + g * 4;
            #pragma unroll
            for (int r = 0; r < 4; r++)
                C[(size_t)(mbase + r) * 1024 + n] = acc[mi][ni][r] + bn;
        }
    }
}

// ---------------- mask pack: int32 -> bit per position ------------------------
__global__ __launch_bounds__(256)
void pack_mask_k(const int* __restrict__ mask, u64* __restrict__ MB)
{
    const int wid  = blockIdx.x * 4 + (threadIdx.x >> 6);
    const int lane = threadIdx.x & 63;
    const int v = mask[(size_t)wid * 64 + lane];
    const u64 bits = __ballot(v != 0);
    if (lane == 0) MB[wid] = bits;
}

// ---------------- flash attention: 32x32 MFMA, in-register P (round-9) --------
__global__ __launch_bounds__(256, 4)
void attn_k(const u16* __restrict__ Q, const u16* __restrict__ K,
            const u16* __restrict__ Vt, const u64* __restrict__ MB,
            u16* __restrict__ CtxP, float* __restrict__ LsumP)
{
    constexpr int S = 2048;
    __shared__ u16 Ks[2][64][64];
    __shared__ u16 Vs[2][64][64];
    const int tid = threadIdx.x, lane = tid & 63, wave = tid >> 6;
    const int l31 = lane & 31, h = lane >> 5, x7 = lane & 7;
    const int hh = blockIdx.y;
    const int b = blockIdx.z >> 1, half = blockIdx.z & 1;
    const int qw = blockIdx.x * 128 + wave * 32;
    const int t0 = half * 16;

    const size_t kgbase = (size_t)b * S * 1024 + hh * 64;
    const size_t vgbase = (size_t)(b * 16 + hh) * 64 * 2048;

    s16x8 qf[4];
    #pragma unroll
    for (int s = 0; s < 4; s++)
        qf[s] = *(const s16x8*)(Q + ((size_t)b * S + qw + l31) * 1024 + hh * 64 + s * 16 + h * 8);

    f32x16 acc[2];
    #pragma unroll
    for (int r = 0; r < 16; r++) { acc[0][r] = 0.f; acc[1][r] = 0.f; }
    float lsum = 0.f;

    const int srl = lane >> 3;
    const int scs = ((lane & 7) ^ srl) * 8;
    auto STAGE = [&](int buf, int kv0) {
        #pragma unroll
        for (int i = 0; i < 2; i++) {
            const int rb = i * 32 + wave * 8;
            gload16(K + kgbase + (size_t)(kv0 + rb + srl) * 1024 + scs, &Ks[buf][rb][0]);
            gload16(Vt + vgbase + (size_t)(rb + srl) * 2048 + kv0 + scs, &Vs[buf][rb][0]);
        }
    };

    const u64* mwp = MB + ((size_t)b * S + qw + l31) * 32 + t0;
    STAGE(0, t0 * 64);

    for (int t = 0; t < 16; t++) {
        const int buf = t & 1;
        const u64 mw = mwp[t];
        if (t < 15) {
            STAGE(buf ^ 1, (t0 + t + 1) * 64);
            asm volatile("s_waitcnt vmcnt(4)" ::: "memory");
        } else {
            asm volatile("s_waitcnt vmcnt(0)" ::: "memory");
        }
        __builtin_amdgcn_s_barrier();
        __builtin_amdgcn_sched_barrier(0);

        f32x16 sc[2];
        #pragma unroll
        for (int r = 0; r < 16; r++) { sc[0][r] = 0.f; sc[1][r] = 0.f; }
        __builtin_amdgcn_s_setprio(1);
        #pragma unroll
        for (int s = 0; s < 4; s++) {
            const int ce = (((s << 1) | h) ^ x7) << 3;
            const s16x8 ka0 = *(const s16x8*)&Ks[buf][l31][ce];
            const s16x8 ka1 = *(const s16x8*)&Ks[buf][32 + l31][ce];
            sc[0] = __builtin_amdgcn_mfma_f32_32x32x16_bf16(ka0, qf[s], sc[0], 0, 0, 0);
            sc[1] = __builtin_amdgcn_mfma_f32_32x32x16_bf16(ka1, qf[s], sc[1], 0, 0, 0);
        }
        __builtin_amdgcn_s_setprio(0);

        s16x8 pa[4];
        #pragma unroll
        for (int kvb = 0; kvb < 2; kvb++) {
            const u32 mh = ((u32)(mw >> (kvb * 32))) >> (h * 4);
            float p[16];
            #pragma unroll
            for (int r = 0; r < 16; r++) {
                const int bit = (r & 3) + ((r >> 2) << 3);
                const float e = __builtin_amdgcn_exp2f(fmaf(sc[kvb][r], 0.18033688f, -11.5415603f));
                p[r] = ((mh >> bit) & 1u) ? e : 0.f;
            }
            lsum += (((p[0] + p[1]) + (p[2] + p[3])) + ((p[4] + p[5]) + (p[6] + p[7])))
                  + (((p[8] + p[9]) + (p[10] + p[11])) + ((p[12] + p[13]) + (p[14] + p[15])));
            #pragma unroll
            for (int sub = 0; sub < 2; sub++) {
                const int base = sub * 8;
                union { u32 w[4]; s16x8 v; } u;
                u.w[0] = cvtpk(p[base + 0], p[base + 1]);
                u.w[1] = cvtpk(p[base + 2], p[base + 3]);
                u.w[2] = cvtpk(p[base + 4], p[base + 5]);
                u.w[3] = cvtpk(p[base + 6], p[base + 7]);
                pa[kvb * 2 + sub] = u.v;
            }
        }

        __builtin_amdgcn_s_setprio(1);
        #pragma unroll
        for (int s = 0; s < 4; s++) {
            const int e0 = (((2 * s)     ^ x7) << 3) + 4 * h;
            const int e1 = (((2 * s + 1) ^ x7) << 3) + 4 * h;
            union { s16x4 q2[2]; s16x8 v; } u0, u1;
            u0.q2[0] = *(const s16x4*)&Vs[buf][l31][e0];
            u0.q2[1] = *(const s16x4*)&Vs[buf][l31][e1];
            u1.q2[0] = *(const s16x4*)&Vs[buf][32 + l31][e0];
            u1.q2[1] = *(const s16x4*)&Vs[buf][32 + l31][e1];
            acc[0] = __builtin_amdgcn_mfma_f32_32x32x16_bf16(pa[s], u0.v, acc[0], 0, 0, 0);
            acc[1] = __builtin_amdgcn_mfma_f32_32x32x16_bf16(pa[s], u1.v, acc[1], 0, 0, 0);
        }
        __builtin_amdgcn_s_setprio(0);
        __builtin_amdgcn_s_barrier();
    }

    lsum += __shfl_xor(lsum, 32, 64);
    const size_t pbase = (size_t)((half * 2 + b) * 16 + hh) * S;
    if (lane < 32) LsumP[pbase + qw + l31] = lsum;

    #pragma unroll
    for (int db = 0; db < 2; db++)
        #pragma unroll
        for (int r = 0; r < 16; r += 2) {
            const int q1 = qw + (r & 3) + ((r >> 2) << 3) + h * 4;
            const u32 w = cvtpk(acc[db][r], acc[db][r + 1]);
            CtxP[(pbase + q1) * 64 + db * 32 + l31]     = (u16)(w & 0xffffu);
            CtxP[(pbase + q1 + 1) * 64 + db * 32 + l31] = (u16)(w >> 16);
        }
}

// ---------------- combine halves: ctx = (a0+a1)/(l0+l1) -----------------------
__global__ __launch_bounds__(256)
void comb_k(const u16* __restrict__ CtxP, const float* __restrict__ LsumP,
            u16* __restrict__ Cx)
{
    const int gid = blockIdx.x * 256 + threadIdx.x;     // 1,048,576 total
    const int d4 = gid & 15;
    const int q  = (gid >> 4) & 2047;
    const int hd = (gid >> 15) & 15;
    const int bb = gid >> 19;
    const size_t i0 = ((size_t)(bb * 16 + hd)) * 2048 + q;
    const size_t i1 = ((size_t)((2 + bb) * 16 + hd)) * 2048 + q;
    const uint2 a = *(const uint2*)&CtxP[i0 * 64 + d4 * 4];
    const uint2 c = *(const uint2*)&CtxP[i1 * 64 + d4 * 4];
    const float rinv = __builtin_amdgcn_rcpf(LsumP[i0] + LsumP[i1]);
    const u32 au[2] = {a.x, a.y}, cu[2] = {c.x, c.y};
    uint2 o;
    u32 ow[2];
    #pragma unroll
    for (int j = 0; j < 2; j++) {
        const float lo = (bf2f(au[j] & 0xffffu) + bf2f(cu[j] & 0xffffu)) * rinv;
        const float hi = (bf2f(au[j] >> 16)     + bf2f(cu[j] >> 16))     * rinv;
        ow[j] = f2bf(lo) | ((u32)f2bf(hi) << 16);
    }
    o.x = ow[0]; o.y = ow[1];
    *(uint2*)&Cx[((size_t)bb * 2048 + q) * 1024 + hd * 64 + d4 * 4] = o;
}

extern "C" void kernel_launch(void* const* d_in, const int* in_sizes, int n_in,
                              void* d_out, int out_size, void* d_ws, size_t ws_size,
                              hipStream_t stream)
{
    const float* query = (const float*)d_in[0];
    const float* key_  = (const float*)d_in[1];
    const float* value = (const float*)d_in[2];
    const int*   mask  = (const int*)d_in[3];
    const float* Wq = (const float*)d_in[4];
    const float* bq = (const float*)d_in[5];
    const float* Wk = (const float*)d_in[6];
    const float* bk = (const float*)d_in[7];
    const float* Wv = (const float*)d_in[8];
    const float* bv = (const float*)d_in[9];
    const float* Wo = (const float*)d_in[10];
    const float* bo = (const float*)d_in[11];

    char* ws = (char*)d_ws;
    u16* CtxP = (u16*)(ws);                        // 16 MB attn partials [0,16)
    u16* Wqb  = (u16*)(ws + (size_t)(24 << 20));   // 2 MB
    u16* Wkb  = (u16*)(ws + (size_t)(26 << 20));   // 2 MB
    u16* Wvb  = (u16*)(ws + (size_t)(28 << 20));   // 2 MB
    u16* Wob  = (u16*)(ws + (size_t)(30 << 20));   // 2 MB
    u16* Qb   = (u16*)(ws + (size_t)(32 << 20));   // 8 MB ; reused as Cx
    u16* Kb   = (u16*)(ws + (size_t)(40 << 20));   // 8 MB
    u16* Vt   = (u16*)(ws + (size_t)(48 << 20));   // 8 MB
    u64* MBp  = (u64*)(ws + (size_t)(56 << 20));   // 1 MB
    float* LsP = (float*)(ws + (size_t)(57 << 20));// 0.5 MB
    u16* Cx   = Qb;   // Qb dead after attn_k

    dim3 bb2(256, 1, 1);
    conv_k<<<dim3(4096, 1, 1), bb2, 0, stream>>>(Wq, Wk, Wv, Wo, Wqb, Wkb, Wvb, Wob);
    qkv_k<<<dim3(32, 8, 3), bb2, 0, stream>>>(query, key_, value, Wqb, Wkb, Wvb,
                                              bq, bk, bv, Qb, Kb, Vt);
    pack_mask_k<<<dim3(32768, 1, 1), bb2, 0, stream>>>(mask, MBp);
    attn_k<<<dim3(16, 16, 4), bb2, 0, stream>>>(Qb, Kb, Vt, MBp, CtxP, LsP);
    comb_k<<<dim3(4096, 1, 1), bb2, 0, stream>>>(CtxP, LsP, Cx);
    og_k<<<dim3(64, 8, 1), bb2, 0, stream>>>(Cx, Wob, bo, (float*)d_out);
}

// Round 14
// 143.418 us; speedup vs baseline: 1.2271x; 1.0305x over previous
//
#include <hip/hip_runtime.h>
#include <hip/hip_bf16.h>

typedef short s16x8 __attribute__((ext_vector_type(8)));
typedef short s16x4 __attribute__((ext_vector_type(4)));
typedef float f32x4 __attribute__((ext_vector_type(4)));
typedef float f32x16 __attribute__((ext_vector_type(16)));
typedef unsigned short u16;
typedef unsigned int u32;
typedef unsigned long long u64;

__device__ __forceinline__ u16 f2bf(float f) {
    union { float f; unsigned u; } c; c.f = f;
    unsigned u = c.u;
    return (u16)((u + 0x7fffu + ((u >> 16) & 1u)) >> 16);
}
__device__ __forceinline__ float bf2f(u32 lo16) {
    union { unsigned u; float f; } c; c.u = lo16 << 16; return c.f;
}
__device__ __forceinline__ u32 cvtpk(float lo, float hi) {
    u32 r;
    asm("v_cvt_pk_bf16_f32 %0, %1, %2" : "=v"(r) : "v"(lo), "v"(hi));
    return r;
}
__device__ __forceinline__ void gload16(const void* g, void* l) {
    __builtin_amdgcn_global_load_lds(
        (const __attribute__((address_space(1))) void*)g,
        (__attribute__((address_space(3))) void*)l, 16, 0, 0);
}

// ---------------- f32 -> bf16 pre-convert (weights only) ----------------------
__global__ __launch_bounds__(256)
void conv_k(const float* __restrict__ wq, const float* __restrict__ wk,
            const float* __restrict__ wv, const float* __restrict__ wo,
            u16* __restrict__ Wqb, u16* __restrict__ Wkb,
            u16* __restrict__ Wvb, u16* __restrict__ Wob)
{
    const int gi = blockIdx.x * 256 + threadIdx.x;   // 1,048,576 float4 groups
    const int seg = gi >> 18;
    const int base = (gi & 262143) * 4;
    const float* src = seg == 0 ? wq : seg == 1 ? wk : seg == 2 ? wv : wo;
    u16* dst = seg == 0 ? Wqb : seg == 1 ? Wkb : seg == 2 ? Wvb : Wob;
    const float4 x = *(const float4*)(src + base);
    uint2 pk;
    pk.x = f2bf(x.x) | ((unsigned)f2bf(x.y) << 16);
    pk.y = f2bf(x.z) | ((unsigned)f2bf(x.w) << 16);
    *(uint2*)(dst + base) = pk;
}

// ---------------- fused QKV projection: C = A(f32) @ W^T + b ------------------
// BM=64 tile (grid 64x8x3 = 6 blocks/CU for latency hiding). A: f32 reg-staged,
// software-pipelined with counted vmcnt + raw barriers. B: bf16 via gload_lds.
__global__ __launch_bounds__(256)
void qkv_k(const float* __restrict__ A0, const float* __restrict__ A1, const float* __restrict__ A2,
           const u16* __restrict__ W0, const u16* __restrict__ W1, const u16* __restrict__ W2,
           const float* __restrict__ b0, const float* __restrict__ b1, const float* __restrict__ b2,
           u16* __restrict__ O0, u16* __restrict__ O1, u16* __restrict__ O2)
{
    __shared__ u16 As[64 * 64];
    __shared__ u16 Bs[128 * 64];
    const int z = blockIdx.z;
    const float* A = z == 0 ? A0 : z == 1 ? A1 : A2;
    const u16* W = z == 0 ? W0 : z == 1 ? W1 : W2;
    const float* bias = z == 0 ? b0 : z == 1 ? b1 : b2;
    u16* O = z == 0 ? O0 : z == 1 ? O1 : O2;

    const int tid = threadIdx.x, lane = tid & 63, wave = tid >> 6;
    const int wm = wave >> 1, wn = wave & 1;
    const int g = lane >> 4, q15 = lane & 15;
    const int m0 = blockIdx.x * 64, n0 = blockIdx.y * 128;
    // B staging (gload_lds, linear dest + inverse-swizzled source)
    const int srl = lane >> 3;
    const int scs = ((lane & 7) ^ srl) * 8;
    const int sw = q15 & 7;
    // A staging (reg): 16 threads/row, one float4 each; 4 passes of 16 rows
    const int arow_l = tid >> 4;
    const int fcol = (tid & 15) * 4;
    const int chunk = fcol >> 3;
    const int within = fcol & 7;

    f32x4 acc[2][4];
    #pragma unroll
    for (int i = 0; i < 2; i++)
        #pragma unroll
        for (int j = 0; j < 4; j++) acc[i][j] = f32x4{0.f, 0.f, 0.f, 0.f};

    // prologue: issue A loads for first tile
    float4 av[4];
    #pragma unroll
    for (int p = 0; p < 4; p++)
        av[p] = *(const float4*)(A + (size_t)(m0 + p * 16 + arow_l) * 1024 + fcol);

    for (int k0 = 0; k0 < 1024; k0 += 64) {
        // barrier #1: all waves done reading LDS from previous MFMA phase
        asm volatile("s_waitcnt lgkmcnt(0)" ::: "memory");
        __builtin_amdgcn_s_barrier();

        // stage B (async, direct to LDS)
        #pragma unroll
        for (int j = 0; j < 4; j++) {
            const int rb = j * 32 + wave * 8;
            gload16(W + (size_t)(n0 + rb + srl) * 1024 + k0 + scs, &Bs[rb * 64]);
        }

        // convert previous av (had full MFMA phase to land)
        uint2 pk[4];
        #pragma unroll
        for (int p = 0; p < 4; p++) {
            pk[p].x = cvtpk(av[p].x, av[p].y);
            pk[p].y = cvtpk(av[p].z, av[p].w);
        }
        // issue next tile's A loads — stay in flight across the barrier
        if (k0 < 960) {
            #pragma unroll
            for (int p = 0; p < 4; p++)
                av[p] = *(const float4*)(A + (size_t)(m0 + p * 16 + arow_l) * 1024 + (k0 + 64) + fcol);
        }
        // write A tile (swizzled layout)
        #pragma unroll
        for (int p = 0; p < 4; p++) {
            const int row = p * 16 + arow_l;
            const int schunk = chunk ^ (row & 7);
            *(uint2*)&As[row * 64 + schunk * 8 + within] = pk[p];
        }

        // barrier #2: B gloads + A writes done; av prefetch (4) stays in flight
        if (k0 < 960)
            asm volatile("s_waitcnt vmcnt(4) lgkmcnt(0)" ::: "memory");
        else
            asm volatile("s_waitcnt vmcnt(0) lgkmcnt(0)" ::: "memory");
        __builtin_amdgcn_s_barrier();
        __builtin_amdgcn_sched_barrier(0);

        #pragma unroll
        for (int kk = 0; kk < 2; kk++) {
            const int ce = ((kk * 4 + g) ^ sw) * 8;
            s16x8 af[2], bfr[4];
            #pragma unroll
            for (int mi = 0; mi < 2; mi++) af[mi]  = *(const s16x8*)&As[(wm * 32 + mi * 16 + q15) * 64 + ce];
            #pragma unroll
            for (int ni = 0; ni < 4; ni++) bfr[ni] = *(const s16x8*)&Bs[(wn * 64 + ni * 16 + q15) * 64 + ce];
            #pragma unroll
            for (int mi = 0; mi < 2; mi++)
                #pragma unroll
                for (int ni = 0; ni < 4; ni++)
                    acc[mi][ni] = __builtin_amdgcn_mfma_f32_16x16x32_bf16(af[mi], bfr[ni], acc[mi][ni], 0, 0, 0);
        }
    }

    #pragma unroll
    for (int mi = 0; mi < 2; mi++) {
        #pragma unroll
        for (int ni = 0; ni < 4; ni++) {
            const int n = n0 + wn * 64 + ni * 16 + q15;
            const float bn = bias[n];
            const int mbase = m0 + wm * 32 + mi * 16 + g * 4;
            if (z < 2) {
                #pragma unroll
                for (int r = 0; r < 4; r++)
                    O[(size_t)(mbase + r) * 1024 + n] = f2bf(acc[mi][ni][r] + bn);
            } else {
                const int bb = mbase >> 11;
                const int s  = mbase & 2047;
                const int hd = n >> 6, d = n & 63;
                u16 hv[4];
                #pragma unroll
                for (int r = 0; r < 4; r++) hv[r] = f2bf(acc[mi][ni][r] + bn);
                uint2 pk2;
                pk2.x = hv[0] | ((unsigned)hv[1] << 16);
                pk2.y = hv[2] | ((unsigned)hv[3] << 16);
                *(uint2*)&O[(((size_t)(bb * 16 + hd) * 64 + d) << 11) + s] = pk2;
            }
        }
    }
}

// ---------------- output projection: C(f32) = A(bf16) @ W^T + b, BK=64 --------
__global__ __launch_bounds__(256)
void og_k(const u16* __restrict__ A, const u16* __restrict__ W,
          const float* __restrict__ bias, float* __restrict__ C)
{
    __shared__ u16 As[64 * 64];
    __shared__ u16 Bs[128 * 64];
    const int tid = threadIdx.x, lane = tid & 63, wave = tid >> 6;
    const int wm = wave >> 1, wn = wave & 1;
    const int g = lane >> 4, q15 = lane & 15;
    const int m0 = blockIdx.x * 64, n0 = blockIdx.y * 128;
    const int srl = lane >> 3;
    const int scs = ((lane & 7) ^ srl) * 8;
    const int sw = q15 & 7;

    f32x4 acc[2][4];
    #pragma unroll
    for (int i = 0; i < 2; i++)
        #pragma unroll
        for (int j = 0; j < 4; j++) acc[i][j] = f32x4{0.f, 0.f, 0.f, 0.f};

    for (int k0 = 0; k0 < 1024; k0 += 64) {
        __syncthreads();
        #pragma unroll
        for (int j = 0; j < 2; j++) {
            const int rb = j * 32 + wave * 8;
            gload16(A + (size_t)(m0 + rb + srl) * 1024 + k0 + scs, &As[rb * 64]);
        }
        #pragma unroll
        for (int j = 0; j < 4; j++) {
            const int rb = j * 32 + wave * 8;
            gload16(W + (size_t)(n0 + rb + srl) * 1024 + k0 + scs, &Bs[rb * 64]);
        }
        __syncthreads();

        #pragma unroll
        for (int kk = 0; kk < 2; kk++) {
            const int ce = ((kk * 4 + g) ^ sw) * 8;
            s16x8 af[2], bfr[4];
            #pragma unroll
            for (int mi = 0; mi < 2; mi++) af[mi]  = *(const s16x8*)&As[(wm * 32 + mi * 16 + q15) * 64 + ce];
            #pragma unroll
            for (int ni = 0; ni < 4; ni++) bfr[ni] = *(const s16x8*)&Bs[(wn * 64 + ni * 16 + q15) * 64 + ce];
            #pragma unroll
            for (int mi = 0; mi < 2; mi++)
                #pragma unroll
                for (int ni = 0; ni < 4; ni++)
                    acc[mi][ni] = __builtin_amdgcn_mfma_f32_16x16x32_bf16(af[mi], bfr[ni], acc[mi][ni], 0, 0, 0);
        }
    }

    #pragma unroll
    for (int mi = 0; mi < 2; mi++) {
        #pragma unroll
        for (int ni = 0; ni < 4; ni++) {
            const int n = n0 + wn * 64 + ni * 16 + q15;
            const float bn = bias[n];
            const int mbase = m0 + wm * 32 + mi * 16 + g * 4;
            #pragma unroll
            for (int r = 0; r < 4; r++)
                C[(size_t)(mbase + r) * 1024 + n] = acc[mi][ni][r] + bn;
        }
    }
}

// ---------------- mask pack: int32 -> bit per position ------------------------
__global__ __launch_bounds__(256)
void pack_mask_k(const int* __restrict__ mask, u64* __restrict__ MB)
{
    const int wid  = blockIdx.x * 4 + (threadIdx.x >> 6);
    const int lane = threadIdx.x & 63;
    const int v = mask[(size_t)wid * 64 + lane];
    const u64 bits = __ballot(v != 0);
    if (lane == 0) MB[wid] = bits;
}

// ---------------- flash attention: 32x32 MFMA, in-register P (round-9) --------
__global__ __launch_bounds__(256, 4)
void attn_k(const u16* __restrict__ Q, const u16* __restrict__ K,
            const u16* __restrict__ Vt, const u64* __restrict__ MB,
            u16* __restrict__ CtxP, float* __restrict__ LsumP)
{
    constexpr int S = 2048;
    __shared__ u16 Ks[2][64][64];
    __shared__ u16 Vs[2][64][64];
    const int tid = threadIdx.x, lane = tid & 63, wave = tid >> 6;
    const int l31 = lane & 31, h = lane >> 5, x7 = lane & 7;
    const int hh = blockIdx.y;
    const int b = blockIdx.z >> 1, half = blockIdx.z & 1;
    const int qw = blockIdx.x * 128 + wave * 32;
    const int t0 = half * 16;

    const size_t kgbase = (size_t)b * S * 1024 + hh * 64;
    const size_t vgbase = (size_t)(b * 16 + hh) * 64 * 2048;

    s16x8 qf[4];
    #pragma unroll
    for (int s = 0; s < 4; s++)
        qf[s] = *(const s16x8*)(Q + ((size_t)b * S + qw + l31) * 1024 + hh * 64 + s * 16 + h * 8);

    f32x16 acc[2];
    #pragma unroll
    for (int r = 0; r < 16; r++) { acc[0][r] = 0.f; acc[1][r] = 0.f; }
    float lsum = 0.f;

    const int srl = lane >> 3;
    const int scs = ((lane & 7) ^ srl) * 8;
    auto STAGE = [&](int buf, int kv0) {
        #pragma unroll
        for (int i = 0; i < 2; i++) {
            const int rb = i * 32 + wave * 8;
            gload16(K + kgbase + (size_t)(kv0 + rb + srl) * 1024 + scs, &Ks[buf][rb][0]);
            gload16(Vt + vgbase + (size_t)(rb + srl) * 2048 + kv0 + scs, &Vs[buf][rb][0]);
        }
    };

    const u64* mwp = MB + ((size_t)b * S + qw + l31) * 32 + t0;
    STAGE(0, t0 * 64);

    for (int t = 0; t < 16; t++) {
        const int buf = t & 1;
        const u64 mw = mwp[t];
        if (t < 15) {
            STAGE(buf ^ 1, (t0 + t + 1) * 64);
            asm volatile("s_waitcnt vmcnt(4)" ::: "memory");
        } else {
            asm volatile("s_waitcnt vmcnt(0)" ::: "memory");
        }
        __builtin_amdgcn_s_barrier();
        __builtin_amdgcn_sched_barrier(0);

        f32x16 sc[2];
        #pragma unroll
        for (int r = 0; r < 16; r++) { sc[0][r] = 0.f; sc[1][r] = 0.f; }
        __builtin_amdgcn_s_setprio(1);
        #pragma unroll
        for (int s = 0; s < 4; s++) {
            const int ce = (((s << 1) | h) ^ x7) << 3;
            const s16x8 ka0 = *(const s16x8*)&Ks[buf][l31][ce];
            const s16x8 ka1 = *(const s16x8*)&Ks[buf][32 + l31][ce];
            sc[0] = __builtin_amdgcn_mfma_f32_32x32x16_bf16(ka0, qf[s], sc[0], 0, 0, 0);
            sc[1] = __builtin_amdgcn_mfma_f32_32x32x16_bf16(ka1, qf[s], sc[1], 0, 0, 0);
        }
        __builtin_amdgcn_s_setprio(0);

        s16x8 pa[4];
        #pragma unroll
        for (int kvb = 0; kvb < 2; kvb++) {
            const u32 mh = ((u32)(mw >> (kvb * 32))) >> (h * 4);
            float p[16];
            #pragma unroll
            for (int r = 0; r < 16; r++) {
                const int bit = (r & 3) + ((r >> 2) << 3);
                const float e = __builtin_amdgcn_exp2f(fmaf(sc[kvb][r], 0.18033688f, -11.5415603f));
                p[r] = ((mh >> bit) & 1u) ? e : 0.f;
            }
            lsum += (((p[0] + p[1]) + (p[2] + p[3])) + ((p[4] + p[5]) + (p[6] + p[7])))
                  + (((p[8] + p[9]) + (p[10] + p[11])) + ((p[12] + p[13]) + (p[14] + p[15])));
            #pragma unroll
            for (int sub = 0; sub < 2; sub++) {
                const int base = sub * 8;
                union { u32 w[4]; s16x8 v; } u;
                u.w[0] = cvtpk(p[base + 0], p[base + 1]);
                u.w[1] = cvtpk(p[base + 2], p[base + 3]);
                u.w[2] = cvtpk(p[base + 4], p[base + 5]);
                u.w[3] = cvtpk(p[base + 6], p[base + 7]);
                pa[kvb * 2 + sub] = u.v;
            }
        }

        __builtin_amdgcn_s_setprio(1);
        #pragma unroll
        for (int s = 0; s < 4; s++) {
            const int e0 = (((2 * s)     ^ x7) << 3) + 4 * h;
            const int e1 = (((2 * s + 1) ^ x7) << 3) + 4 * h;
            union { s16x4 q2[2]; s16x8 v; } u0, u1;
            u0.q2[0] = *(const s16x4*)&Vs[buf][l31][e0];
            u0.q2[1] = *(const s16x4*)&Vs[buf][l31][e1];
            u1.q2[0] = *(const s16x4*)&Vs[buf][32 + l31][e0];
            u1.q2[1] = *(const s16x4*)&Vs[buf][32 + l31][e1];
            acc[0] = __builtin_amdgcn_mfma_f32_32x32x16_bf16(pa[s], u0.v, acc[0], 0, 0, 0);
            acc[1] = __builtin_amdgcn_mfma_f32_32x32x16_bf16(pa[s], u1.v, acc[1], 0, 0, 0);
        }
        __builtin_amdgcn_s_setprio(0);
        __builtin_amdgcn_s_barrier();
    }

    lsum += __shfl_xor(lsum, 32, 64);
    const size_t pbase = (size_t)((half * 2 + b) * 16 + hh) * S;
    if (lane < 32) LsumP[pbase + qw + l31] = lsum;

    #pragma unroll
    for (int db = 0; db < 2; db++)
        #pragma unroll
        for (int r = 0; r < 16; r += 2) {
            const int q1 = qw + (r & 3) + ((r >> 2) << 3) + h * 4;
            const u32 w = cvtpk(acc[db][r], acc[db][r + 1]);
            CtxP[(pbase + q1) * 64 + db * 32 + l31]     = (u16)(w & 0xffffu);
            CtxP[(pbase + q1 + 1) * 64 + db * 32 + l31] = (u16)(w >> 16);
        }
}

// ---------------- combine halves: ctx = (a0+a1)/(l0+l1) -----------------------
__global__ __launch_bounds__(256)
void comb_k(const u16* __restrict__ CtxP, const float* __restrict__ LsumP,
            u16* __restrict__ Cx)
{
    const int gid = blockIdx.x * 256 + threadIdx.x;     // 1,048,576 total
    const int d4 = gid & 15;
    const int q  = (gid >> 4) & 2047;
    const int hd = (gid >> 15) & 15;
    const int bb = gid >> 19;
    const size_t i0 = ((size_t)(bb * 16 + hd)) * 2048 + q;
    const size_t i1 = ((size_t)((2 + bb) * 16 + hd)) * 2048 + q;
    const uint2 a = *(const uint2*)&CtxP[i0 * 64 + d4 * 4];
    const uint2 c = *(const uint2*)&CtxP[i1 * 64 + d4 * 4];
    const float rinv = __builtin_amdgcn_rcpf(LsumP[i0] + LsumP[i1]);
    const u32 au[2] = {a.x, a.y}, cu[2] = {c.x, c.y};
    uint2 o;
    u32 ow[2];
    #pragma unroll
    for (int j = 0; j < 2; j++) {
        const float lo = (bf2f(au[j] & 0xffffu) + bf2f(cu[j] & 0xffffu)) * rinv;
        const float hi = (bf2f(au[j] >> 16)     + bf2f(cu[j] >> 16))     * rinv;
        ow[j] = f2bf(lo) | ((u32)f2bf(hi) << 16);
    }
    o.x = ow[0]; o.y = ow[1];
    *(uint2*)&Cx[((size_t)bb * 2048 + q) * 1024 + hd * 64 + d4 * 4] = o;
}

extern "C" void kernel_launch(void* const* d_in, const int* in_sizes, int n_in,
                              void* d_out, int out_size, void* d_ws, size_t ws_size,
                              hipStream_t stream)
{
    const float* query = (const float*)d_in[0];
    const float* key_  = (const float*)d_in[1];
    const float* value = (const float*)d_in[2];
    const int*   mask  = (const int*)d_in[3];
    const float* Wq = (const float*)d_in[4];
    const float* bq = (const float*)d_in[5];
    const float* Wk = (const float*)d_in[6];
    const float* bk = (const float*)d_in[7];
    const float* Wv = (const float*)d_in[8];
    const float* bv = (const float*)d_in[9];
    const float* Wo = (const float*)d_in[10];
    const float* bo = (const float*)d_in[11];

    char* ws = (char*)d_ws;
    u16* CtxP = (u16*)(ws);                        // 16 MB attn partials [0,16)
    u16* Wqb  = (u16*)(ws + (size_t)(24 << 20));   // 2 MB
    u16* Wkb  = (u16*)(ws + (size_t)(26 << 20));   // 2 MB
    u16* Wvb  = (u16*)(ws + (size_t)(28 << 20));   // 2 MB
    u16* Wob  = (u16*)(ws + (size_t)(30 << 20));   // 2 MB
    u16* Qb   = (u16*)(ws + (size_t)(32 << 20));   // 8 MB ; reused as Cx
    u16* Kb   = (u16*)(ws + (size_t)(40 << 20));   // 8 MB
    u16* Vt   = (u16*)(ws + (size_t)(48 << 20));   // 8 MB
    u64* MBp  = (u64*)(ws + (size_t)(56 << 20));   // 1 MB
    float* LsP = (float*)(ws + (size_t)(57 << 20));// 0.5 MB
    u16* Cx   = Qb;   // Qb dead after attn_k

    dim3 bb2(256, 1, 1);
    conv_k<<<dim3(4096, 1, 1), bb2, 0, stream>>>(Wq, Wk, Wv, Wo, Wqb, Wkb, Wvb, Wob);
    qkv_k<<<dim3(64, 8, 3), bb2, 0, stream>>>(query, key_, value, Wqb, Wkb, Wvb,
                                              bq, bk, bv, Qb, Kb, Vt);
    pack_mask_k<<<dim3(32768, 1, 1), bb2, 0, stream>>>(mask, MBp);
    attn_k<<<dim3(16, 16, 4), bb2, 0, stream>>>(Qb, Kb, Vt, MBp, CtxP, LsP);
    comb_k<<<dim3(4096, 1, 1), bb2, 0, stream>>>(CtxP, LsP, Cx);
    og_k<<<dim3(64, 8, 1), bb2, 0, stream>>>(Cx, Wob, bo, (float*)d_out);
}